// Round 1
// baseline (161.878 us; speedup 1.0000x reference)
//
#include <hip/hip_runtime.h>
#include <math.h>

// Problem constants: B=8192, V=8, J=32
#define B_TOT 8192
#define V_N 8
#define J_N 32
#define GRID_N (B_TOT / 4)   // 2048 blocks, 4 batches (waves) per block

#define SCALE_KPS 0.1f
#define THRESH 100.0f
#define THRESH_BETA 63.09573444801932f  // 100^0.9

// smooth-MSE branch: d>100 ? d^0.1 * 100^0.9 : d
// __builtin_amdgcn_logf = v_log_f32 (log2), __builtin_amdgcn_exp2f = v_exp_f32
__device__ __forceinline__ float smooth_term(float d) {
    return (d > THRESH)
        ? __builtin_amdgcn_exp2f(0.1f * __builtin_amdgcn_logf(d)) * THRESH_BETA
        : d;
}

// One WAVE per batch. Lane l: view v = l>>3, joint-group t = l&7 (joints
// 4t..4t+3 processed serially). All big loads are float4 / fully coalesced.
// NEW vs prior round:
//  - M = K*cam folded ONCE per lane (3x4), per-joint cost 21 -> 9 FMA and
//    k0..k8/c0..c2 die early => smaller live set, targeting VGPR<=64 so
//    __launch_bounds__(256,8) gives 8 waves/SIMD (32/CU) instead of 4.
//  - Final reduction fused: last-arriving block folds the 2048 partials.
//    Cross-XCD visibility via agent-scope atomic store/load (per-XCD L2 is
//    NOT coherent; plain loads could hit stale poison lines). Counter is
//    zeroed each iteration by a 4-byte memset node in the captured graph.
__global__ __launch_bounds__(256, 8) void qpl_fused(
    const float* __restrict__ Kmat,   // [B,V,3,3]
    const float* __restrict__ cam,    // [B,V,3,4]
    const float* __restrict__ kps,    // [B,J,3]
    const float* __restrict__ init,   // [B,V,J,2]
    float* __restrict__ partial,      // [GRID_N] in d_ws
    unsigned int* __restrict__ counter, // 1 uint in d_ws, pre-zeroed
    float* __restrict__ out)          // scalar result
{
    __shared__ float s_acc[4];
    __shared__ unsigned int s_old;

    const int tid  = threadIdx.x;
    const int wave = tid >> 6;
    const int lane = tid & 63;
    const int v    = lane >> 3;   // view 0..7
    const int t    = lane & 7;    // joint group: joints 4t..4t+3
    const int b    = blockIdx.x * 4 + wave;

    // cam[b,v]: 48B, 16B-aligned, uniform within 8-lane group
    const float* cv = cam + (size_t)b * (V_N * 12) + v * 12;
    const float4 c0 = ((const float4*)cv)[0];
    const float4 c1 = ((const float4*)cv)[1];
    const float4 c2 = ((const float4*)cv)[2];

    // K[b,v]: 36B stride -> odd v misaligned for float4; scalar broadcast loads
    const float* kv = Kmat + (size_t)b * (V_N * 9) + v * 9;
    const float k0 = kv[0], k1 = kv[1], k2 = kv[2];
    const float k3 = kv[3], k4 = kv[4], k5 = kv[5];
    const float k6 = kv[6], k7 = kv[7], k8 = kv[8];

    // kps[b, 4t..4t+3, :]: floats [12t, 12t+12), 16B-aligned (48B stride)
    const float4* kp4 = (const float4*)(kps + (size_t)b * (J_N * 3) + t * 12);
    const float4 f0 = kp4[0], f1 = kp4[1], f2 = kp4[2];

    // init[b, v, 4t..4t+3, :]: lane reads bytes [32*lane, 32*lane+32)
    const float4* ib = (const float4*)(init + (size_t)b * (V_N * J_N * 2) + lane * 8);
    const float4 q0 = ib[0], q1 = ib[1];

    // Fold intrinsics into extrinsics: M = K * cam (3x4). img = M * Xh.
    // Computed while kps/init loads are still in flight; kills k*/c* regs.
    float4 m0, m1, m2;
    m0.x = k0*c0.x + k1*c1.x + k2*c2.x;  m0.y = k0*c0.y + k1*c1.y + k2*c2.y;
    m0.z = k0*c0.z + k1*c1.z + k2*c2.z;  m0.w = k0*c0.w + k1*c1.w + k2*c2.w;
    m1.x = k3*c0.x + k4*c1.x + k5*c2.x;  m1.y = k3*c0.y + k4*c1.y + k5*c2.y;
    m1.z = k3*c0.z + k4*c1.z + k5*c2.z;  m1.w = k3*c0.w + k4*c1.w + k5*c2.w;
    m2.x = k6*c0.x + k7*c1.x + k8*c2.x;  m2.y = k6*c0.y + k7*c1.y + k8*c2.y;
    m2.z = k6*c0.z + k7*c1.z + k8*c2.z;  m2.w = k6*c0.w + k7*c1.w + k8*c2.w;

    const float xs[4]  = {f0.x, f0.w, f1.z, f2.y};
    const float ys[4]  = {f0.y, f1.x, f1.w, f2.z};
    const float zs[4]  = {f0.z, f1.y, f2.x, f2.w};
    const float ikx[4] = {q0.x, q0.z, q1.x, q1.z};
    const float iky[4] = {q0.y, q0.w, q1.y, q1.w};

    float sum_diff = 0.0f, sum_p2 = 0.0f, sum_i2 = 0.0f;

    #pragma unroll
    for (int m = 0; m < 4; ++m) {
        const float i0 = m0.w + m0.x * xs[m] + m0.y * ys[m] + m0.z * zs[m];
        const float i1 = m1.w + m1.x * xs[m] + m1.y * ys[m] + m1.z * zs[m];
        const float i2 = m2.w + m2.x * xs[m] + m2.y * ys[m] + m2.z * zs[m];

        const float r  = __builtin_amdgcn_rcpf(i2);   // 1-ulp, tolerance is 358 abs
        const float p0 = i0 * r;
        const float p1 = i1 * r;

        float d0 = (p0 - ikx[m]) * SCALE_KPS; d0 *= d0;
        float d1 = (p1 - iky[m]) * SCALE_KPS; d1 *= d1;

        sum_diff += smooth_term(d0) + smooth_term(d1);
        sum_p2   += p0 * p0 + p1 * p1;
        sum_i2   += ikx[m] * ikx[m] + iky[m] * iky[m];
    }

    // reduce over the 8 lanes of this view-group (masks 1,2,4 stay in-group)
    #pragma unroll
    for (int m = 1; m <= 4; m <<= 1) {
        sum_diff += __shfl_xor(sum_diff, m);
        sum_p2   += __shfl_xor(sum_p2, m);
        sum_i2   += __shfl_xor(sum_i2, m);
    }

    const float penal = fabsf(sqrtf(sum_p2 * __builtin_amdgcn_rcpf(sum_i2)) - 1.0f);
    float acc = (sum_diff * 0.5f) * penal;   // uniform within 8-lane group

    // fold the 8 DISTINCT view-groups: each view added exactly once
    acc += __shfl_xor(acc, 8);
    acc += __shfl_xor(acc, 16);
    acc += __shfl_xor(acc, 32);

    if (lane == 0) s_acc[wave] = acc;
    __syncthreads();

    // Block partial -> global; last-arriving block does the final fold.
    if (tid == 0) {
        const float bs = s_acc[0] + s_acc[1] + s_acc[2] + s_acc[3];
        // agent-scope store: visible device-wide (bypasses per-XCD L2 staleness)
        __hip_atomic_store(&partial[blockIdx.x], bs,
                           __ATOMIC_RELAXED, __HIP_MEMORY_SCOPE_AGENT);
        __threadfence();  // release partial before announcing arrival
        s_old = __hip_atomic_fetch_add(counter, 1u,
                                       __ATOMIC_ACQ_REL, __HIP_MEMORY_SCOPE_AGENT);
    }
    __syncthreads();
    if (s_old != GRID_N - 1) return;

    // Last block: all 2047 other partials are globally visible (their
    // release fences ordered store->counter). Acquire + agent-scope loads.
    __threadfence();
    float tsum = 0.0f;
    #pragma unroll
    for (int k = 0; k < GRID_N / 256; ++k)
        tsum += __hip_atomic_load(&partial[tid + k * 256],
                                  __ATOMIC_RELAXED, __HIP_MEMORY_SCOPE_AGENT);

    #pragma unroll
    for (int m = 32; m >= 1; m >>= 1) tsum += __shfl_xor(tsum, m);

    if (lane == 0) s_acc[wave] = tsum;
    __syncthreads();
    if (tid == 0)
        out[0] = (s_acc[0] + s_acc[1] + s_acc[2] + s_acc[3])
               * (1.0f / (float)(B_TOT * V_N));
}

extern "C" void kernel_launch(void* const* d_in, const int* in_sizes, int n_in,
                              void* d_out, int out_size, void* d_ws, size_t ws_size,
                              hipStream_t stream) {
    const float* Kmat = (const float*)d_in[0];  // [B,V,3,3]
    const float* cam  = (const float*)d_in[1];  // [B,V,3,4]
    const float* kps  = (const float*)d_in[2];  // [B,J,3]
    const float* init = (const float*)d_in[3];  // [B,V,J,2]
    float* partial = (float*)d_ws;                                   // 2048 floats
    unsigned int* counter = (unsigned int*)((char*)d_ws + GRID_N * sizeof(float));
    float* out = (float*)d_out;

    // zero the arrival counter each iteration (ws is re-poisoned by harness);
    // async memset is graph-capture-safe and becomes a cheap memset node.
    hipMemsetAsync(counter, 0, sizeof(unsigned int), stream);
    qpl_fused<<<GRID_N, 256, 0, stream>>>(Kmat, cam, kps, init, partial, counter, out);
}

// Round 4
// 77.244 us; speedup vs baseline: 2.0957x; 2.0957x over previous
//
#include <hip/hip_runtime.h>
#include <math.h>

// Problem constants: B=8192, V=8, J=32
#define B_TOT 8192
#define V_N 8
#define J_N 32
#define GRID_N (B_TOT / 4)   // 2048 blocks, 4 batches (waves) per block

#define SCALE_KPS 0.1f
#define THRESH 100.0f
#define THRESH_BETA 63.09573444801932f  // 100^0.9

// smooth-MSE branch: d>100 ? d^0.1 * 100^0.9 : d
// __builtin_amdgcn_logf = v_log_f32 (log2), __builtin_amdgcn_exp2f = v_exp_f32
__device__ __forceinline__ float smooth_term(float d) {
    return (d > THRESH)
        ? __builtin_amdgcn_exp2f(0.1f * __builtin_amdgcn_logf(d)) * THRESH_BETA
        : d;
}

// One WAVE per batch. Lane l: view v = l>>3, joint-group t = l&7 (joints
// 4t..4t+3 processed serially). All big loads are float4 / fully coalesced.
//
// SESSION LESSONS (hard-won, do not regress):
//  - R1: agent-scope ACQ_REL atomics / __threadfence() per block emit
//    buffer_wbl2/buffer_inv (per-XCD L2 flush) -> 2048 serialized flushes,
//    kernel 105-122us @ 1.5% HBM. Never fence for result publication.
//  - R2: memset/atomicAdd on d_out from kernel_launch host code tripwired
//    (direct launch_once read NaN: harness d_out poison raced our memset).
//    d_out must be written ONLY by a kernel plain store. Two-kernel
//    structure (partials in d_ws, tiny reduce kernel) is the proven shape.
//  - R1 counters: M = K*cam fold + __launch_bounds__(256,8) achieves
//    VGPR=32 (8 waves/SIMD). Keep both.
//  - R3: container infra failure, kernel never ran — this is a resubmit.
__global__ __launch_bounds__(256, 8) void qpl_fused(
    const float* __restrict__ Kmat,   // [B,V,3,3]
    const float* __restrict__ cam,    // [B,V,3,4]
    const float* __restrict__ kps,    // [B,J,3]
    const float* __restrict__ init,   // [B,V,J,2]
    float* __restrict__ partial)      // [GRID_N] in d_ws
{
    __shared__ float s_acc[4];

    const int tid  = threadIdx.x;
    const int wave = tid >> 6;
    const int lane = tid & 63;
    const int v    = lane >> 3;   // view 0..7
    const int t    = lane & 7;    // joint group: joints 4t..4t+3
    const int b    = blockIdx.x * 4 + wave;

    // init[b, v, 4t..4t+3, :]: lane reads bytes [32*lane, 32*lane+32).
    // Issued first: this is the BW bulk (16.8 MB of the 25.4 MB total).
    const float4* ib = (const float4*)(init + (size_t)b * (V_N * J_N * 2) + lane * 8);
    const float4 q0 = ib[0], q1 = ib[1];

    // kps[b, 4t..4t+3, :]: floats [12t, 12t+12), 16B-aligned (48B stride)
    const float4* kp4 = (const float4*)(kps + (size_t)b * (J_N * 3) + t * 12);
    const float4 f0 = kp4[0], f1 = kp4[1], f2 = kp4[2];

    // cam[b,v]: 48B, 16B-aligned, uniform within 8-lane group
    const float* cv = cam + (size_t)b * (V_N * 12) + v * 12;
    const float4 c0 = ((const float4*)cv)[0];
    const float4 c1 = ((const float4*)cv)[1];
    const float4 c2 = ((const float4*)cv)[2];

    // K[b,v]: 36B stride -> odd v misaligned for float4; scalar broadcast loads
    const float* kv = Kmat + (size_t)b * (V_N * 9) + v * 9;
    const float k0 = kv[0], k1 = kv[1], k2 = kv[2];
    const float k3 = kv[3], k4 = kv[4], k5 = kv[5];
    const float k6 = kv[6], k7 = kv[7], k8 = kv[8];

    // Fold intrinsics into extrinsics: M = K * cam (3x4). img = M * Xh.
    // Per-joint cost drops 21 -> 9 FMA; k*/c* live ranges die here (VGPR=32).
    float4 m0, m1, m2;
    m0.x = k0*c0.x + k1*c1.x + k2*c2.x;  m0.y = k0*c0.y + k1*c1.y + k2*c2.y;
    m0.z = k0*c0.z + k1*c1.z + k2*c2.z;  m0.w = k0*c0.w + k1*c1.w + k2*c2.w;
    m1.x = k3*c0.x + k4*c1.x + k5*c2.x;  m1.y = k3*c0.y + k4*c1.y + k5*c2.y;
    m1.z = k3*c0.z + k4*c1.z + k5*c2.z;  m1.w = k3*c0.w + k4*c1.w + k5*c2.w;
    m2.x = k6*c0.x + k7*c1.x + k8*c2.x;  m2.y = k6*c0.y + k7*c1.y + k8*c2.y;
    m2.z = k6*c0.z + k7*c1.z + k8*c2.z;  m2.w = k6*c0.w + k7*c1.w + k8*c2.w;

    const float xs[4]  = {f0.x, f0.w, f1.z, f2.y};
    const float ys[4]  = {f0.y, f1.x, f1.w, f2.z};
    const float zs[4]  = {f0.z, f1.y, f2.x, f2.w};
    const float ikx[4] = {q0.x, q0.z, q1.x, q1.z};
    const float iky[4] = {q0.y, q0.w, q1.y, q1.w};

    float sum_diff = 0.0f, sum_p2 = 0.0f, sum_i2 = 0.0f;

    #pragma unroll
    for (int m = 0; m < 4; ++m) {
        const float i0 = m0.w + m0.x * xs[m] + m0.y * ys[m] + m0.z * zs[m];
        const float i1 = m1.w + m1.x * xs[m] + m1.y * ys[m] + m1.z * zs[m];
        const float i2 = m2.w + m2.x * xs[m] + m2.y * ys[m] + m2.z * zs[m];

        const float r  = __builtin_amdgcn_rcpf(i2);   // 1-ulp, tolerance is 358 abs
        const float p0 = i0 * r;
        const float p1 = i1 * r;

        float d0 = (p0 - ikx[m]) * SCALE_KPS; d0 *= d0;
        float d1 = (p1 - iky[m]) * SCALE_KPS; d1 *= d1;

        sum_diff += smooth_term(d0) + smooth_term(d1);
        sum_p2   += p0 * p0 + p1 * p1;
        sum_i2   += ikx[m] * ikx[m] + iky[m] * iky[m];
    }

    // reduce over the 8 lanes of this view-group (masks 1,2,4 stay in-group)
    #pragma unroll
    for (int m = 1; m <= 4; m <<= 1) {
        sum_diff += __shfl_xor(sum_diff, m);
        sum_p2   += __shfl_xor(sum_p2, m);
        sum_i2   += __shfl_xor(sum_i2, m);
    }

    const float penal = fabsf(sqrtf(sum_p2 * __builtin_amdgcn_rcpf(sum_i2)) - 1.0f);
    float acc = (sum_diff * 0.5f) * penal;   // uniform within 8-lane group

    // fold the 8 DISTINCT view-groups: each view added exactly once
    acc += __shfl_xor(acc, 8);
    acc += __shfl_xor(acc, 16);
    acc += __shfl_xor(acc, 32);

    if (lane == 0) s_acc[wave] = acc;
    __syncthreads();
    if (tid == 0)
        partial[blockIdx.x] = s_acc[0] + s_acc[1] + s_acc[2] + s_acc[3];
}

// Fold 2048 per-block partials into the scalar output (plain store to d_out;
// cross-kernel visibility of partial[] is guaranteed by the dispatch boundary).
__global__ __launch_bounds__(256) void qpl_reduce(
    const float* __restrict__ partial, float* __restrict__ out)
{
    __shared__ float s_w[4];
    const float4 a = ((const float4*)partial)[threadIdx.x];
    const float4 b = ((const float4*)partial)[threadIdx.x + 256];
    float t = (a.x + a.y) + (a.z + a.w) + (b.x + b.y) + (b.z + b.w);

    #pragma unroll
    for (int m = 32; m >= 1; m >>= 1) t += __shfl_xor(t, m);

    if ((threadIdx.x & 63) == 0) s_w[threadIdx.x >> 6] = t;
    __syncthreads();

    if (threadIdx.x == 0) {
        const float tot = s_w[0] + s_w[1] + s_w[2] + s_w[3];
        out[0] = tot * (1.0f / (float)(B_TOT * V_N));
    }
}

extern "C" void kernel_launch(void* const* d_in, const int* in_sizes, int n_in,
                              void* d_out, int out_size, void* d_ws, size_t ws_size,
                              hipStream_t stream) {
    const float* Kmat = (const float*)d_in[0];  // [B,V,3,3]
    const float* cam  = (const float*)d_in[1];  // [B,V,3,4]
    const float* kps  = (const float*)d_in[2];  // [B,J,3]
    const float* init = (const float*)d_in[3];  // [B,V,J,2]
    float* partial = (float*)d_ws;              // 2048 floats
    float* out     = (float*)d_out;

    qpl_fused<<<GRID_N, 256, 0, stream>>>(Kmat, cam, kps, init, partial);
    qpl_reduce<<<1, 256, 0, stream>>>(partial, out);
}